// Round 1
// baseline (76.329 us; speedup 1.0000x reference)
//
#include <hip/hip_runtime.h>

// casConv2d: B=1, C=128, H=W=32, OC=128, K=3, pad=1, stride=1.
// L = 1024, CKK = 1152 = 36 exact 32-tap chunks (reference front-pad chunk == 0).
//
// Round-9. Evidence: top-5 rocprof dispatches are all ~43us 256MiB ws-poison
// fills -> both app kernels < 43us; prior session pinned gemm at ~4us, so
// fused_mq ~25us is the kernel-side bottleneck. Diagnosis: planes[j][l][oc]
// makes each mq block gather 36 scattered 512B segments at ~512KB stride
// across 18.9MB (no locality, reader XCD != writer XCD). Fix: transpose the
// intermediate to planes[l][j][oc] so each mq block reads ONE contiguous
// 18.4KB region; swizzle mq blockIdx so reader XCD == writer XCD (gemm block
// id = bx + 16*j => XCD = bx%8, j-independent); restructure mq as 2 px/block
// with all-36-chunks-per-thread in VGPRs, shuffle-based minmax reduction
// (3 barriers instead of ~10), float2 output stores.
#define L_     1024
#define CKK_   1152
#define QMAX_  255.0f
#define NCH    36
#define LSTR_  (NCH * 128)   // per-pixel stride in floats: 36 chunks x 128 oc

// grid = (16 l-tiles of 64 px, 36 chunks) = 576 blocks, 256 threads.
// Block owns ALL 128 oc x 64 px x 1 chunk.
__global__ __launch_bounds__(256) void gemm_chunks(
    const float* __restrict__ x,      // [128][32][32]
    const float* __restrict__ w,      // [128][1152]
    float* __restrict__ planes)       // [1024][36][128]  (l major, oc minor)
{
    __shared__ __align__(16) float Wb[32][132];  // [tap][oc], pad 132
    __shared__ __align__(16) float xs[32][64];   // [tap][l-local]

    const int t   = threadIdx.x;
    const int l0  = blockIdx.x * 64;             // 64 px = output rows oh0, oh0+1
    const int j   = blockIdx.y;
    const int d0  = j * 32;
    const int oh0 = l0 >> 5;

    // ---- stage W chunk (16 KB): 4 float4 global loads per thread ----
    float4 wld[4];
    int    wo[4], wk[4];
#pragma unroll
    for (int it = 0; it < 4; it++) {
        const int f4 = it * 256 + t;             // 1024 float4s = 128 oc x 8
        wo[it]  = f4 >> 3;                       // oc
        wk[it]  = (f4 & 7) * 4;                  // tap base
        wld[it] = *(const float4*)(w + wo[it] * CKK_ + d0 + wk[it]);
    }

    // ---- stage x chunk (8 KB): 8 predicated scalar loads per thread ----
    float xl[8];
    int   xk[8], xll[8];
#pragma unroll
    for (int it = 0; it < 8; it++) {
        const int e  = it * 256 + t;             // 2048 = 32 taps x 64 px
        const int k  = e >> 6, ll = e & 63;
        const int d  = d0 + k;                   // uniform tap id
        const int c  = d / 9, r = d - 9 * c;
        const int kh = r / 3, kw = r - 3 * kh;
        const int iy = oh0 + (ll >> 5) + kh - 1;
        const int ix = (ll & 31) + kw - 1;
        const bool ok = ((unsigned)iy < 32u) & ((unsigned)ix < 32u);
        const int idx = ok ? (c * 1024 + iy * 32 + ix) : 0;
        const float v = x[idx];
        xl[it] = ok ? v : 0.f;
        xk[it] = k; xll[it] = ll;
    }

#pragma unroll
    for (int it = 0; it < 4; it++) {
        Wb[wk[it] + 0][wo[it]] = wld[it].x;
        Wb[wk[it] + 1][wo[it]] = wld[it].y;
        Wb[wk[it] + 2][wo[it]] = wld[it].z;
        Wb[wk[it] + 3][wo[it]] = wld[it].w;
    }
#pragma unroll
    for (int it = 0; it < 8; it++)
        xs[xk[it]][xll[it]] = xl[it];
    __syncthreads();

    // ---- compute: 4 oc x 8 px per thread, 1024 FMA, 32 indep chains ----
    const int oc0 = (t & 31) * 4;
    const int ll0 = (t >> 5) * 8;
    float acc[4][8];
#pragma unroll
    for (int r = 0; r < 4; r++)
#pragma unroll
        for (int i = 0; i < 8; i++) acc[r][i] = 0.f;

#pragma unroll
    for (int k = 0; k < 32; k++) {
        const float4 wv = *(const float4*)&Wb[k][oc0];
        const float4 xa = *(const float4*)&xs[k][ll0];
        const float4 xb = *(const float4*)&xs[k][ll0 + 4];
        acc[0][0] = fmaf(wv.x, xa.x, acc[0][0]);
        acc[0][1] = fmaf(wv.x, xa.y, acc[0][1]);
        acc[0][2] = fmaf(wv.x, xa.z, acc[0][2]);
        acc[0][3] = fmaf(wv.x, xa.w, acc[0][3]);
        acc[0][4] = fmaf(wv.x, xb.x, acc[0][4]);
        acc[0][5] = fmaf(wv.x, xb.y, acc[0][5]);
        acc[0][6] = fmaf(wv.x, xb.z, acc[0][6]);
        acc[0][7] = fmaf(wv.x, xb.w, acc[0][7]);
        acc[1][0] = fmaf(wv.y, xa.x, acc[1][0]);
        acc[1][1] = fmaf(wv.y, xa.y, acc[1][1]);
        acc[1][2] = fmaf(wv.y, xa.z, acc[1][2]);
        acc[1][3] = fmaf(wv.y, xa.w, acc[1][3]);
        acc[1][4] = fmaf(wv.y, xb.x, acc[1][4]);
        acc[1][5] = fmaf(wv.y, xb.y, acc[1][5]);
        acc[1][6] = fmaf(wv.y, xb.z, acc[1][6]);
        acc[1][7] = fmaf(wv.y, xb.w, acc[1][7]);
        acc[2][0] = fmaf(wv.z, xa.x, acc[2][0]);
        acc[2][1] = fmaf(wv.z, xa.y, acc[2][1]);
        acc[2][2] = fmaf(wv.z, xa.z, acc[2][2]);
        acc[2][3] = fmaf(wv.z, xa.w, acc[2][3]);
        acc[2][4] = fmaf(wv.z, xb.x, acc[2][4]);
        acc[2][5] = fmaf(wv.z, xb.y, acc[2][5]);
        acc[2][6] = fmaf(wv.z, xb.z, acc[2][6]);
        acc[2][7] = fmaf(wv.z, xb.w, acc[2][7]);
        acc[3][0] = fmaf(wv.w, xa.x, acc[3][0]);
        acc[3][1] = fmaf(wv.w, xa.y, acc[3][1]);
        acc[3][2] = fmaf(wv.w, xa.z, acc[3][2]);
        acc[3][3] = fmaf(wv.w, xa.w, acc[3][3]);
        acc[3][4] = fmaf(wv.w, xb.x, acc[3][4]);
        acc[3][5] = fmaf(wv.w, xb.y, acc[3][5]);
        acc[3][6] = fmaf(wv.w, xb.z, acc[3][6]);
        acc[3][7] = fmaf(wv.w, xb.w, acc[3][7]);
    }

    // ---- epilogue: 512B contiguous per half-wave row, stride 18.4KB ----
    float* dst = planes + (size_t)(l0 + ll0) * LSTR_ + (size_t)j * 128 + oc0;
#pragma unroll
    for (int i = 0; i < 8; i++)
        *(float4*)(dst + (size_t)i * LSTR_) =
            make_float4(acc[0][i], acc[1][i], acc[2][i], acc[3][i]);
}

// Fused minmax+quant, 2 px per block: thread owns all 36 chunks of one
// (oc, px) in VGPRs. Each block reads ONE contiguous 36.9KB region.
// Block swizzle: tile = b & 15 (bijective), so reader XCD (b%8) == writer
// XCD (tile%8) -> planes tile is L2-local.
__global__ __launch_bounds__(256) void fused_mq(
    const float* __restrict__ planes,  // [1024][36][128]
    const float* __restrict__ bias,    // [128]
    float* __restrict__ out)           // [128][1024]
{
    __shared__ float red[8];           // [wave]=mn, [4+wave]=mx
    __shared__ float sp[2][3];         // per-px {scale, zp, inv}
    __shared__ float qb[2][128];
    const int t  = threadIdx.x;
    const int b  = blockIdx.x;
    const int m  = (b & 15) * 32 + (b >> 4);   // pixel-pair index, XCD-aligned
    const int l0 = m << 1;
    const int oc = t & 127, px = t >> 7;       // waves 0-1: px0, waves 2-3: px1
    const int l  = l0 + px;

    const float* p = planes + (size_t)l * LSTR_ + oc;
    float v[36];
#pragma unroll
    for (int j = 0; j < 36; j++) v[j] = p[(size_t)j * 128];

    float s = 0.f;
#pragma unroll
    for (int j = 0; j < 36; j++) s += v[j];
    const float tot = s + bias[oc];

    // wave-level minmax over 64 lanes (lanes = 64 consecutive oc)
    float mn = tot, mx = tot;
#pragma unroll
    for (int off = 32; off > 0; off >>= 1) {
        mn = fminf(mn, __shfl_xor(mn, off));
        mx = fmaxf(mx, __shfl_xor(mx, off));
    }
    const int wv = t >> 6;
    if ((t & 63) == 0) { red[wv] = mn; red[4 + wv] = mx; }
    __syncthreads();

    if ((t & 127) == 0) {              // t==0 handles px0, t==128 handles px1
        const int w0 = px << 1;
        const float amn = fminf(red[w0], red[w0 + 1]);
        const float amx = fmaxf(red[4 + w0], red[4 + w0 + 1]);
        const float sv  = (amx - amn) / QMAX_;
        float z = -amn / sv;
        z = fmaxf(z, 0.f);             // fmaxf(NaN,0)=0 matches where(isnan,0)
        z = fminf(z, QMAX_);
        z = truncf(z);
        sp[px][0] = sv; sp[px][1] = z; sp[px][2] = 1.0f / sv;
    }
    __syncthreads();

    const float sc = sp[px][0], zv = sp[px][1], iv = sp[px][2];
    float q = 0.f;
#pragma unroll
    for (int j = 0; j < 36; j++) {
        float qn = rintf(v[j] * iv) + zv;   // rintf == round-half-even
        qn = fminf(fmaxf(qn, 0.f), QMAX_);
        q += (qn - zv) * sc;
    }
    qb[px][oc] = q;
    __syncthreads();

    if (t < 128)
        *(float2*)(out + (size_t)t * L_ + l0) = make_float2(qb[0][t], qb[1][t]);
}

// ---- small-ws fallback (~520 KB): known-correct two-pass ----
template <bool QUANT>
__global__ __launch_bounds__(256) void cas_direct(
    const float* __restrict__ x, const float* __restrict__ w,
    float* __restrict__ out, const float* __restrict__ scale,
    const float* __restrict__ zp, const float* __restrict__ inv)
{
    const int t = threadIdx.x;
    const int ocBase = blockIdx.x * 16;
    const int l = blockIdx.y * 256 + t;
    const int oh = l >> 5, ow = l & 31;

    float sc = 0.f, zv = 0.f, iv = 0.f;
    if (QUANT) { sc = scale[l]; zv = zp[l]; iv = inv[l]; }

    float acc[16];
#pragma unroll
    for (int oc = 0; oc < 16; oc++) acc[oc] = 0.f;

    for (int j = 0; j < NCH; j++) {
        const int d0 = j * 32;
        float xv[32];
#pragma unroll
        for (int dd = 0; dd < 32; dd++) {
            const int d = d0 + dd, c = d / 9, r = d - 9 * c;
            const int kh = r / 3, kw = r - 3 * kh;
            const int off = c * 1024 + (kh - 1) * 32 + (kw - 1);
            const bool ok = ((unsigned)(oh + kh - 1) < 32u) &
                            ((unsigned)(ow + kw - 1) < 32u);
            const int idx = ok ? (off + l) : 0;
            const float vv = x[idx];
            xv[dd] = ok ? vv : 0.f;
        }
#pragma unroll
        for (int oc = 0; oc < 16; oc++) {
            const float4* wp = (const float4*)(w + (ocBase + oc) * CKK_ + d0);
            float pa = 0.f, pb = 0.f;
#pragma unroll
            for (int k4 = 0; k4 < 8; k4++) {
                const float4 wv = wp[k4];
                float& pr = (k4 < 4) ? pa : pb;
                pr = fmaf(wv.x, xv[4 * k4 + 0], pr);
                pr = fmaf(wv.y, xv[4 * k4 + 1], pr);
                pr = fmaf(wv.z, xv[4 * k4 + 2], pr);
                pr = fmaf(wv.w, xv[4 * k4 + 3], pr);
            }
            const float s2 = pa + pb;
            if (QUANT) {
                float qn = rintf(s2 * iv) + zv;
                qn = fminf(fmaxf(qn, 0.f), QMAX_);
                acc[oc] += (qn - zv) * sc;
            } else {
                acc[oc] += s2;
            }
        }
    }
#pragma unroll
    for (int oc = 0; oc < 16; oc++)
        out[(ocBase + oc) * L_ + l] = acc[oc];
}

__global__ __launch_bounds__(256) void minmax_conv(
    const float* __restrict__ conv, const float* __restrict__ bias,
    float* __restrict__ scale, float* __restrict__ zp, float* __restrict__ inv)
{
    __shared__ float smn[16][17], smx[16][17];
    const int t = threadIdx.x, li = t & 15, g = t >> 4;
    const int l = blockIdx.x * 16 + li;
    float mn = INFINITY, mx = -INFINITY;
#pragma unroll
    for (int i = 0; i < 8; i++) {
        const int oc = g * 8 + i;
        const float v = conv[oc * L_ + l] + bias[oc];
        mn = fminf(mn, v); mx = fmaxf(mx, v);
    }
    smn[g][li] = mn; smx[g][li] = mx;
    __syncthreads();
    if (t < 16) {
        const int l2 = blockIdx.x * 16 + t;
        float amn = smn[0][t], amx = smx[0][t];
#pragma unroll
        for (int g2 = 1; g2 < 16; g2++) {
            amn = fminf(amn, smn[g2][t]); amx = fmaxf(amx, smx[g2][t]);
        }
        const float s = (amx - amn) / QMAX_;
        float z = -amn / s;
        z = fminf(fmaxf(z, 0.f), QMAX_);
        z = truncf(z);
        scale[l2] = s; zp[l2] = z; inv[l2] = 1.0f / s;
    }
}

extern "C" void kernel_launch(void* const* d_in, const int* in_sizes, int n_in,
                              void* d_out, int out_size, void* d_ws, size_t ws_size,
                              hipStream_t stream) {
    const float* x    = (const float*)d_in[0];  // 128*32*32
    const float* w    = (const float*)d_in[1];  // 128*1152
    const float* bias = (const float*)d_in[2];  // 128
    float* out = (float*)d_out;                 // 128*1024
    float* ws  = (float*)d_ws;

    const size_t main_need = (size_t)L_ * LSTR_ * 4;   // 18.9 MB
    if (ws_size >= main_need) {
        float* planes = ws;                     // [1024][36][128]
        gemm_chunks<<<dim3(16, NCH), 256, 0, stream>>>(x, w, planes);
        fused_mq<<<512, 256, 0, stream>>>(planes, bias, out);
    } else {
        float* conv  = ws;                      // 131072
        float* scale = conv + 131072;
        float* zpv   = scale + 1024;
        float* inv   = zpv + 1024;
        cas_direct<false><<<dim3(8, 4), 256, 0, stream>>>(x, w, conv, nullptr, nullptr, nullptr);
        minmax_conv<<<64, 256, 0, stream>>>(conv, bias, scale, zpv, inv);
        cas_direct<true><<<dim3(8, 4), 256, 0, stream>>>(x, w, out, scale, zpv, inv);
    }
}